// Round 1
// baseline (258.768 us; speedup 1.0000x reference)
//
#include <hip/hip_runtime.h>

// FCOS loss, 5 FPN levels, B=16, C=80.
// Level pixel counts: 12800, 3200, 800, 208, 56  -> total 17064.

namespace {
constexpr int NPIX = 17064;
constexpr int C_   = 80;

struct LevelPtrs {
    const float* conf[5];
    const float* loc[5];
    const float* center[5];
    const float* ltrb[5];
    const int*   cls[5];
    const int*   pos[5];
};
}  // namespace

// acc layout in d_ws (floats): [0..15] loss_conf, [16..31] loss_l, [32..47] loss_center,
// then 16 ints for pos counts.
__global__ __launch_bounds__(256) void fcos_main(LevelPtrs P,
                                                 float* __restrict__ acc_conf,
                                                 float* __restrict__ acc_l,
                                                 float* __restrict__ acc_c,
                                                 int* __restrict__ acc_n) {
    const int b = blockIdx.y;
    const int g = blockIdx.x * 256 + threadIdx.x;

    float s_conf = 0.f, s_l = 0.f, s_c = 0.f;
    int s_n = 0;

    if (g < NPIX) {
        int l, p, HW;
        if (g < 12800)      { l = 0; p = g;         HW = 12800; }
        else if (g < 16000) { l = 1; p = g - 12800; HW = 3200; }
        else if (g < 16800) { l = 2; p = g - 16000; HW = 800; }
        else if (g < 17008) { l = 3; p = g - 16800; HW = 208; }
        else                { l = 4; p = g - 17008; HW = 56; }

        const size_t bpix = (size_t)b * HW + p;
        const int clsv = P.cls[l][bpix];
        const bool posm = (P.pos[l][bpix] == 0);

        if (posm) {
            const float* loc = P.loc[l]  + (size_t)b * 4 * HW + p;
            const float* ltr = P.ltrb[l] + (size_t)b * 4 * HW + p;
            float lp = loc[0] * 32.f, tp = loc[HW] * 32.f,
                  rp = loc[2 * HW] * 32.f, bp2 = loc[3 * HW] * 32.f;
            float lt = ltr[0] * 32.f, tt = ltr[HW] * 32.f,
                  rt = ltr[2 * HW] * 32.f, bt = ltr[3 * HW] * 32.f;

            float iw = fmaxf(fminf(lp, lt) + fminf(rp, rt), 0.f);
            float ih = fmaxf(fminf(tp, tt) + fminf(bp2, bt), 0.f);
            float inter = iw * ih;
            float area_p = fmaxf(lp + rp, 0.f) * fmaxf(tp + bp2, 0.f);
            float area_t = (lt + rt) * (tt + bt);
            float iou = inter / (area_p + area_t - inter + 1e-6f);
            s_l = -logf(iou + 1e-6f);

            float ctr = sqrtf((fminf(lt, rt) / (fmaxf(lt, rt) + 1e-6f)) *
                              (fminf(tt, bt) / (fmaxf(tt, bt) + 1e-6f)));
            float cp = P.center[l][bpix];
            cp = fminf(fmaxf(cp, 1e-8f), 0.99999999f);  // matches jnp.clip in f32
            s_c = -(ctr * logf(cp) + (1.f - ctr) * logf(1.f - cp));
            s_n = 1;
        }

        const float* conf = P.conf[l] + (size_t)b * C_ * HW + p;
#pragma unroll 8
        for (int c = 0; c < C_; ++c) {
            float v = conf[(size_t)c * HW];
            float pc = fminf(fmaxf(v, 1e-8f), 0.99999999f);
            float term = -0.75f * pc * pc * logf(1.f - pc);
            if (posm && c == clsv) {
                float om = 1.f - pc;
                term = -0.25f * om * om * logf(pc);
            }
            s_conf += term;
        }
    }

    // wave64 shuffle reduction
    for (int o = 32; o > 0; o >>= 1) {
        s_conf += __shfl_down(s_conf, o, 64);
        s_l    += __shfl_down(s_l, o, 64);
        s_c    += __shfl_down(s_c, o, 64);
        s_n    += __shfl_down(s_n, o, 64);
    }
    if ((threadIdx.x & 63) == 0) {
        atomicAdd(&acc_conf[b], s_conf);
        atomicAdd(&acc_l[b], s_l);
        atomicAdd(&acc_c[b], s_c);
        atomicAdd(&acc_n[b], s_n);
    }
}

__global__ void fcos_final(const float* __restrict__ accf,
                           const int* __restrict__ accn,
                           float* __restrict__ out) {
    const int t = threadIdx.x;  // 64 threads
    float v = 0.f;
    if (t < 16) {
        float lc = accf[t], ll = accf[16 + t], lctr = accf[32 + t];
        int n = accn[t];
        float pf = fmaxf((float)n, 1.f);
        v = (n > 0) ? (lctr + (lc + ll) / pf) : (lctr + lc + ll);
    }
    for (int o = 32; o > 0; o >>= 1) v += __shfl_down(v, o, 64);
    if (t == 0) out[0] = v * (1.f / 16.f);
}

extern "C" void kernel_launch(void* const* d_in, const int* in_sizes, int n_in,
                              void* d_out, int out_size, void* d_ws, size_t ws_size,
                              hipStream_t stream) {
    LevelPtrs P;
    for (int l = 0; l < 5; ++l) {
        P.conf[l]   = (const float*)d_in[l * 6 + 0];
        P.loc[l]    = (const float*)d_in[l * 6 + 1];
        P.center[l] = (const float*)d_in[l * 6 + 2];
        P.ltrb[l]   = (const float*)d_in[l * 6 + 3];
        P.cls[l]    = (const int*)d_in[l * 6 + 4];
        P.pos[l]    = (const int*)d_in[l * 6 + 5];
    }
    float* accf = (float*)d_ws;
    int*   accn = (int*)((char*)d_ws + 48 * sizeof(float));

    hipMemsetAsync(d_ws, 0, 64 * sizeof(float), stream);

    dim3 grid((NPIX + 255) / 256, 16);
    fcos_main<<<grid, 256, 0, stream>>>(P, accf, accf + 16, accf + 32, accn);
    fcos_final<<<1, 64, 0, stream>>>(accf, accn, (float*)d_out);
}